// Round 1
// baseline (245.118 us; speedup 1.0000x reference)
//
#include <hip/hip_runtime.h>

// Cumulative product along last dim of (4096, 32768) fp32.
// One block per row; 1024 threads x 32 contiguous elements each.
// 3-level scan: registers (sequential) -> wave (shfl_up, 64 lanes) -> block (LDS wave totals).

#define COLS 32768
#define TPB  1024
#define EPT  (COLS / TPB)   // 32 elements per thread

__global__ __launch_bounds__(TPB) void cumprod_rows(const float* __restrict__ x,
                                                    float* __restrict__ out) {
    const int row  = blockIdx.x;
    const int tid  = threadIdx.x;
    const int lane = tid & 63;
    const int wid  = tid >> 6;          // wave id within block, 0..15

    const size_t rowbase = (size_t)row * (size_t)COLS;
    const size_t chunk   = rowbase + (size_t)tid * EPT;

    // ---- load 32 contiguous floats as 8 x float4 ----
    float v[EPT];
    float4* vv = reinterpret_cast<float4*>(v);
    const float4* xin = reinterpret_cast<const float4*>(x + chunk);
    #pragma unroll
    for (int k = 0; k < EPT / 4; ++k) vv[k] = xin[k];

    // ---- level 1: sequential inclusive scan in registers ----
    #pragma unroll
    for (int i = 1; i < EPT; ++i) v[i] *= v[i - 1];

    // ---- level 2: wave-wide inclusive scan of thread totals (64 lanes) ----
    float s = v[EPT - 1];
    #pragma unroll
    for (int off = 1; off < 64; off <<= 1) {
        float u = __shfl_up(s, off);
        if (lane >= off) s *= u;
    }
    // exclusive prefix within the wave
    float ex = __shfl_up(s, 1);
    if (lane == 0) ex = 1.0f;

    // ---- level 3: scan of wave totals through LDS ----
    __shared__ float wtot[TPB / 64];    // 16 wave totals
    if (lane == 63) wtot[wid] = s;      // lane 63 holds the wave's inclusive total
    __syncthreads();

    float pre = ex;
    for (int w = 0; w < wid; ++w) pre *= wtot[w];   // broadcast reads, conflict-free

    // ---- apply prefix and store ----
    #pragma unroll
    for (int i = 0; i < EPT; ++i) v[i] *= pre;

    float4* o = reinterpret_cast<float4*>(out + chunk);
    #pragma unroll
    for (int k = 0; k < EPT / 4; ++k) o[k] = vv[k];
}

extern "C" void kernel_launch(void* const* d_in, const int* in_sizes, int n_in,
                              void* d_out, int out_size, void* d_ws, size_t ws_size,
                              hipStream_t stream) {
    const float* x = (const float*)d_in[0];
    float* out = (float*)d_out;
    const int rows = out_size / COLS;   // 4096
    cumprod_rows<<<rows, TPB, 0, stream>>>(x, out);
}

// Round 3
// 236.106 us; speedup vs baseline: 1.0382x; 1.0382x over previous
//
#include <hip/hip_runtime.h>

// Cumulative product along last dim of (4096, 32768) fp32.
// One block per row; 1024 threads. Row split into 8 sub-blocks of 4096 elems;
// each thread owns one contiguous float4 per sub-block -> every vmem
// instruction is a fully-coalesced 1KB/wave access.
// Scan: float4 register scan -> wave shfl scan (8 indep chains) ->
// single-barrier block combine via 8x16 wave-total table in LDS.

#define COLS 32768
#define TPB  1024
#define SUB  8
#define SUBCOLS (COLS / SUB)      // 4096 = TPB * 4
#define NWAVE (TPB / 64)          // 16

typedef float f32x4 __attribute__((ext_vector_type(4)));

__global__ __launch_bounds__(TPB) void cumprod_rows(const float* __restrict__ x,
                                                    float* __restrict__ out) {
    const int row  = blockIdx.x;
    const int tid  = threadIdx.x;
    const int lane = tid & 63;
    const int wid  = tid >> 6;                 // 0..15

    const size_t rowbase = (size_t)row * (size_t)COLS;

    // ---- coalesced loads: one float4 per sub-block per thread ----
    f32x4 d[SUB];
    #pragma unroll
    for (int s = 0; s < SUB; ++s) {
        const f32x4* p = reinterpret_cast<const f32x4*>(x + rowbase + s * SUBCOLS + tid * 4);
        d[s] = __builtin_nontemporal_load(p);
    }

    // ---- level 1: register scan within each float4 ----
    #pragma unroll
    for (int s = 0; s < SUB; ++s) {
        d[s][1] *= d[s][0];
        d[s][2] *= d[s][1];
        d[s][3] *= d[s][2];
    }

    // ---- level 2: wave-wide inclusive scan of thread totals, 8 indep chains ----
    float incl[SUB], ex[SUB];
    #pragma unroll
    for (int s = 0; s < SUB; ++s) incl[s] = d[s][3];
    #pragma unroll
    for (int off = 1; off < 64; off <<= 1) {
        #pragma unroll
        for (int s = 0; s < SUB; ++s) {
            float u = __shfl_up(incl[s], off);
            if (lane >= off) incl[s] *= u;
        }
    }
    #pragma unroll
    for (int s = 0; s < SUB; ++s) {
        ex[s] = __shfl_up(incl[s], 1);
        if (lane == 0) ex[s] = 1.0f;
    }

    // ---- level 3: block combine, single barrier ----
    __shared__ float wtot[SUB][NWAVE];
    if (lane == 63) {
        #pragma unroll
        for (int s = 0; s < SUB; ++s) wtot[s][wid] = incl[s];
    }
    __syncthreads();

    // carry chain across sub-blocks; all LDS reads are wave-uniform broadcasts
    float pre[SUB];
    float carry = 1.0f;
    #pragma unroll
    for (int s = 0; s < SUB; ++s) {
        float wp = 1.0f;                       // product of preceding waves' totals
        for (int w = 0; w < wid; ++w) wp *= wtot[s][w];
        pre[s] = carry * wp * ex[s];
        float bt = wp;                         // full sub-block total
        for (int w = wid; w < NWAVE; ++w) bt *= wtot[s][w];
        carry *= bt;
    }

    // ---- apply prefix, coalesced stores ----
    #pragma unroll
    for (int s = 0; s < SUB; ++s) {
        d[s][0] *= pre[s];
        d[s][1] *= pre[s];
        d[s][2] *= pre[s];
        d[s][3] *= pre[s];
        f32x4* p = reinterpret_cast<f32x4*>(out + rowbase + s * SUBCOLS + tid * 4);
        __builtin_nontemporal_store(d[s], p);
    }
}

extern "C" void kernel_launch(void* const* d_in, const int* in_sizes, int n_in,
                              void* d_out, int out_size, void* d_ws, size_t ws_size,
                              hipStream_t stream) {
    const float* x = (const float*)d_in[0];
    float* out = (float*)d_out;
    const int rows = out_size / COLS;   // 4096
    cumprod_rows<<<rows, TPB, 0, stream>>>(x, out);
}

// Round 4
// 229.398 us; speedup vs baseline: 1.0685x; 1.0292x over previous
//
#include <hip/hip_runtime.h>

// Cumulative product along last dim of (4096, 32768) fp32.
// ONE WAVE PER ROW — no barriers, no LDS tables, no block-level phasing.
// Each wave streams its row in 128 chunks of 256 elems (64 lanes x float4,
// 1KB fully-coalesced per vmem instruction) with a 4-deep register ring
// prefetch (statically indexed). Per chunk: in-thread scan (3 muls) ->
// 6-step shfl_up wave scan -> serial scalar carry -> coalesced store.
// Chunk scans are independent; only the carry multiply is serial, so the
// unrolled loop software-pipelines and loads stay in flight continuously.

#define COLS   32768
#define TPB    256
#define WPB    (TPB / 64)        // 4 waves (rows) per block
#define CHUNK  256               // elems per chunk: 64 lanes * 4
#define NCHUNK (COLS / CHUNK)    // 128
#define PF     4                 // prefetch depth in chunks

typedef float f32x4 __attribute__((ext_vector_type(4)));

__global__ __launch_bounds__(TPB) void cumprod_rows(const float* __restrict__ x,
                                                    float* __restrict__ out) {
    const int lane = threadIdx.x & 63;
    const int wid  = threadIdx.x >> 6;
    const int row  = blockIdx.x * WPB + wid;

    const size_t base = (size_t)row * (size_t)COLS + (size_t)lane * 4;
    const float* px = x + base;
    float*       po = out + base;

    // ---- prime the prefetch ring (static indices only) ----
    f32x4 buf[PF];
    #pragma unroll
    for (int j = 0; j < PF; ++j)
        buf[j] = __builtin_nontemporal_load(
            reinterpret_cast<const f32x4*>(px + j * CHUNK));

    float carry = 1.0f;

    for (int cc = 0; cc < NCHUNK; cc += PF) {
        #pragma unroll
        for (int j = 0; j < PF; ++j) {
            f32x4 v = buf[j];

            // refill this ring slot from PF chunks ahead (wave-uniform branch)
            const int nc = cc + PF + j;
            if (nc < NCHUNK)
                buf[j] = __builtin_nontemporal_load(
                    reinterpret_cast<const f32x4*>(px + nc * CHUNK));

            // in-thread inclusive scan of the 4 elements
            v[1] *= v[0];
            v[2] *= v[1];
            v[3] *= v[2];

            // wave-wide inclusive scan of per-thread totals (64 lanes)
            float t = v[3];
            #pragma unroll
            for (int off = 1; off < 64; off <<= 1) {
                float u = __shfl_up(t, off);
                if (lane >= off) t *= u;
            }
            // exclusive prefix for this lane
            float ex = __shfl_up(t, 1);
            if (lane == 0) ex = 1.0f;

            const float m = carry * ex;

            // chunk total -> next carry (the only serial dependency)
            carry *= __shfl(t, 63);

            f32x4 o;
            o[0] = v[0] * m;
            o[1] = v[1] * m;
            o[2] = v[2] * m;
            o[3] = v[3] * m;
            __builtin_nontemporal_store(
                o, reinterpret_cast<f32x4*>(po + (cc + j) * CHUNK));
        }
    }
}

extern "C" void kernel_launch(void* const* d_in, const int* in_sizes, int n_in,
                              void* d_out, int out_size, void* d_ws, size_t ws_size,
                              hipStream_t stream) {
    const float* x = (const float*)d_in[0];
    float* out = (float*)d_out;
    const int rows = out_size / COLS;          // 4096
    cumprod_rows<<<rows / WPB, TPB, 0, stream>>>(x, out);
}